// Round 9
// baseline (6737.301 us; speedup 1.0000x reference)
//
#include <hip/hip_runtime.h>
#include <hip/hip_bf16.h>
#include <stdint.h>

#define BATCH 4096
#define UNITS 1024
#define NSTEP 128

typedef __attribute__((ext_vector_type(4))) float f32x4;
typedef __attribute__((ext_vector_type(8))) short s16x8;

__device__ __forceinline__ void gload16(const void* g, void* l) {
  __builtin_amdgcn_global_load_lds(
      (const __attribute__((address_space(1))) unsigned int*)g,
      (__attribute__((address_space(3))) unsigned int*)l, 16, 0, 0);
}

__device__ __forceinline__ void block_barrier() {
  asm volatile("" ::: "memory");
  __builtin_amdgcn_s_barrier();
  asm volatile("" ::: "memory");
}

__device__ __forceinline__ float fsigmoid(float x) {
  return 1.0f / (1.0f + __expf(-x));
}
__device__ __forceinline__ float ftanh(float x) {
  return 1.0f - 2.0f / (__expf(2.0f * x) + 1.0f);
}

// 16-MFMA quadrant cluster; MO/GO must be literals (static acc indexing).
#define MMA(Afr, Bfr, MO, GO)                                              \
  do {                                                                     \
    __builtin_amdgcn_s_setprio(1);                                         \
    _Pragma("unroll") for (int m_ = 0; m_ < 4; ++m_)                       \
    _Pragma("unroll") for (int g_ = 0; g_ < 2; ++g_)                       \
    _Pragma("unroll") for (int k_ = 0; k_ < 2; ++k_)                       \
        acc[(MO) + m_][(GO) + g_] =                                        \
            __builtin_amdgcn_mfma_f32_16x16x32_bf16(                       \
                Afr[m_][k_], Bfr[g_][k_], acc[(MO) + m_][(GO) + g_],       \
                0, 0, 0);                                                  \
    __builtin_amdgcn_s_setprio(0);                                         \
  } while (0)

// Transpose recurrent_kernel [1024][4096] f32 -> permuted bf16 [4096][1024].
// orig n = g*1024 + u, u = q*64 + wc*16 + ul
//   -> n' = q*256 + (g>>1)*128 + wc*32 + (g&1)*16 + ul
__global__ void prep_weights(const float* __restrict__ R,
                             const float* __restrict__ ker,   // [4096]
                             const float* __restrict__ dw,    // [1024]
                             __hip_bfloat16* __restrict__ Rt0,
                             __hip_bfloat16* __restrict__ Rt1) {
  __shared__ float tile[32][33];
  __shared__ float dws[32];
  const int n0 = blockIdx.x * 32;
  const int k0 = blockIdx.y * 32;
  const int tx = threadIdx.x;       // 0..31
  const int ty = threadIdx.y;       // 0..7
#pragma unroll
  for (int i = 0; i < 4; ++i) {
    int k = ty + i * 8;
    tile[k][tx] = R[(size_t)(k0 + k) * 4096 + n0 + tx];
  }
  if (ty == 0) dws[tx] = dw[k0 + tx];
  __syncthreads();
#pragma unroll
  for (int i = 0; i < 4; ++i) {
    int n = ty + i * 8;
    float v = tile[tx][n];
    int gn = n0 + n, gk = k0 + tx;
    int g = gn >> 10, u = gn & 1023;
    int q = u >> 6, wc = (u >> 4) & 3, ul = u & 15;
    int np = q * 256 + (g >> 1) * 128 + wc * 32 + (g & 1) * 16 + ul;
    size_t o = (size_t)np * 1024 + gk;
    Rt0[o] = __float2bfloat16(v);
    Rt1[o] = __float2bfloat16(v + dws[tx] * ker[gn]);
  }
}

__global__ void prep_state(const float* __restrict__ feat,   // [4096][512]
                           const float* __restrict__ bias,   // [4096]
                           const float* __restrict__ ker,    // [4096]
                           const float* __restrict__ db,     // [1]
                           float* __restrict__ bias1,
                           __hip_bfloat16* __restrict__ hA,
                           float* __restrict__ c,
                           float* __restrict__ out) {
  const int total = BATCH * UNITS;
  const float dbv = db[0];
  for (int i = blockIdx.x * blockDim.x + threadIdx.x; i < total;
       i += gridDim.x * blockDim.x) {
    int b = i >> 10, u = i & 1023;
    float v = feat[b * 512 + (u & 511)];   // concat([features,features])
    hA[i] = __float2bfloat16(v);
    c[i] = v;
    if (i < 4096) bias1[i] = bias[i] + dbv * ker[i];
    if (i < BATCH * NSTEP) out[i] = dbv;
  }
}

// ===================== REAL STEP KERNEL (R4-identical) =====================
__global__ __launch_bounds__(512, 2) void lstm_step(
    const __hip_bfloat16* __restrict__ hin,   // [4096][1024]
    const __hip_bfloat16* __restrict__ Bp,    // permuted Rt [4096][1024]
    const float* __restrict__ biasv,          // [4096] (orig layout)
    float* __restrict__ c,                    // [4096][1024] f32
    __hip_bfloat16* __restrict__ hout,        // [4096][1024]
    const float* __restrict__ dw,             // [1024]
    float* __restrict__ out, int t) {
  extern __shared__ char lds[];   // 131072 = 2 buf x (A 32K + B 32K)
  const int tid = threadIdx.x;
  const int lane = tid & 63;
  const int w = tid >> 6;
  const int l15 = lane & 15;
  const int lhi = lane >> 4;
  const int wr = w >> 2;          // 0..1
  const int wc = w & 3;           // 0..3

  const int bi = blockIdx.x;
  const int xcd = bi & 7, slot = bi >> 3;
  const int bx = (xcd & 3) * 4 + (slot & 3);   // 0..15 (batch tiles)
  const int by = (xcd >> 2) * 8 + (slot >> 2); // 0..15 (unit tiles)

  const int ucol = by * 64 + wc * 16 + l15;
  const float dwv = dw[ucol];

  f32x4 acc[8][4];
#pragma unroll
  for (int g = 0; g < 4; ++g) {
    float bg = biasv[g * 1024 + ucol];
#pragma unroll
    for (int m = 0; m < 8; ++m) acc[m][g] = (f32x4){bg, bg, bg, bg};
  }
  asm volatile("" :: "v"(dwv));

  const char* Asrc = (const char*)(hin + (size_t)bx * 256 * 1024);
  const char* Bsrc = (const char*)(Bp + (size_t)by * 256 * 1024);
  const int swz = (l15 & 7) << 4;

  auto STAGE = [&](const char* src, int rowoff, int kt, char* dstbase) {
#pragma unroll
    for (int i = 0; i < 2; ++i) {
      int chunk = i * 512 + tid;
      int row = chunk >> 3, s = chunk & 7;
      gload16(src + (size_t)(rowoff + row) * 2048 + kt * 128 +
                  ((s * 16) ^ ((row & 7) << 4)),
              dstbase + i * 8192 + w * 1024 + lane * 16);
    }
  };

  auto RD_AL = [&](const char* Ab, s16x8 (&d)[4][2]) {
#pragma unroll
    for (int m = 0; m < 4; ++m) {
      int row = wr * 64 + m * 16 + l15;
#pragma unroll
      for (int kk = 0; kk < 2; ++kk)
        d[m][kk] = *(const s16x8*)(Ab + row * 128 + ((kk * 64 + lhi * 16) ^ swz));
    }
  };
  auto RD_AH = [&](const char* Ab, s16x8 (&d)[4][2]) {
#pragma unroll
    for (int m = 0; m < 4; ++m) {
      int row = 128 + wr * 64 + m * 16 + l15;
#pragma unroll
      for (int kk = 0; kk < 2; ++kk)
        d[m][kk] = *(const s16x8*)(Ab + row * 128 + ((kk * 64 + lhi * 16) ^ swz));
    }
  };
  auto RD_BL = [&](const char* Bb, s16x8 (&d)[2][2]) {
#pragma unroll
    for (int g = 0; g < 2; ++g) {
      int row = wc * 32 + g * 16 + l15;
#pragma unroll
      for (int kk = 0; kk < 2; ++kk)
        d[g][kk] = *(const s16x8*)(Bb + row * 128 + ((kk * 64 + lhi * 16) ^ swz));
    }
  };
  auto RD_BH = [&](const char* Bb, s16x8 (&d)[2][2]) {
#pragma unroll
    for (int g = 0; g < 2; ++g) {
      int row = 128 + wc * 32 + g * 16 + l15;
#pragma unroll
      for (int kk = 0; kk < 2; ++kk)
        d[g][kk] = *(const s16x8*)(Bb + row * 128 + ((kk * 64 + lhi * 16) ^ swz));
    }
  };

  STAGE(Asrc, 0,   0, lds);                    // h1 A-lo
  STAGE(Bsrc, 0,   0, lds + 32768);            // h2 B-lo
  STAGE(Bsrc, 128, 0, lds + 32768 + 16384);    // h3 B-hi
  STAGE(Asrc, 128, 0, lds + 16384);            // h4 A-hi

  for (int kt = 0; kt < 16; ++kt) {
    const char* Ab = lds + (kt & 1) * 65536;
    const char* Bb = Ab + 32768;
    char* Sd = lds + ((kt + 1) & 1) * 65536;
    const bool pf = (kt < 15);

    s16x8 al[4][2], bl[2][2], bh[2][2], ah[4][2];

    // P1
    asm volatile("s_waitcnt vmcnt(4)" ::: "memory");
    block_barrier();
    RD_AL(Ab, al);
    RD_BL(Bb, bl);
    if (pf) STAGE(Asrc, 0, kt + 1, Sd);
    asm volatile("s_waitcnt lgkmcnt(0)" ::: "memory");
    __builtin_amdgcn_sched_barrier(0);
    MMA(al, bl, 0, 0);

    // P2
    if (pf) asm volatile("s_waitcnt vmcnt(4)" ::: "memory");
    else    asm volatile("s_waitcnt vmcnt(2)" ::: "memory");
    block_barrier();
    RD_BH(Bb, bh);
    if (pf) STAGE(Bsrc, 0, kt + 1, Sd + 32768);
    asm volatile("s_waitcnt lgkmcnt(0)" ::: "memory");
    __builtin_amdgcn_sched_barrier(0);
    MMA(al, bh, 0, 2);

    // P3
    if (pf) asm volatile("s_waitcnt vmcnt(4)" ::: "memory");
    else    asm volatile("s_waitcnt vmcnt(0)" ::: "memory");
    block_barrier();
    RD_AH(Ab, ah);
    if (pf) STAGE(Bsrc, 128, kt + 1, Sd + 32768 + 16384);
    asm volatile("s_waitcnt lgkmcnt(0)" ::: "memory");
    __builtin_amdgcn_sched_barrier(0);
    MMA(ah, bh, 4, 2);

    // P4
    if (pf) STAGE(Asrc, 128, kt + 1, Sd + 16384);
    MMA(ah, bl, 4, 0);
  }

#pragma unroll
  for (int m = 0; m < 8; ++m) {
#pragma unroll
    for (int j = 0; j < 4; ++j) {
      int b = bx * 256 + (m >> 2) * 128 + wr * 64 + (m & 3) * 16 + lhi * 4 + j;
      size_t ci = (size_t)b * 1024 + ucol;
      float zi = acc[m][0][j], zf = acc[m][1][j];
      float zg = acc[m][2][j], zo = acc[m][3][j];
      float ig = fsigmoid(zi), fg = fsigmoid(zf);
      float gg = ftanh(zg), og = fsigmoid(zo);
      float cn = fg * c[ci] + ig * gg;
      c[ci] = cn;
      float hn = og * ftanh(cn);
      hout[ci] = __float2bfloat16(hn);
      float p = hn * dwv;
      p += __shfl_xor(p, 1);
      p += __shfl_xor(p, 2);
      p += __shfl_xor(p, 4);
      p += __shfl_xor(p, 8);
      if (l15 == 0) atomicAdd(&out[(size_t)b * NSTEP + t], p);
    }
  }
}

// NOTE (R4 sync argument, unchanged): per phase the entry vmcnt(4)+barrier
// guarantees the half about to be ds_read has been staged by ALL waves
// (symmetric per-wave issue counts); each wave's lgkmcnt(0) precedes the next
// phase's barrier so no read outlives its buffer; P-tail uses vmcnt(2)/(0).

// ===================== ABLATION PROBES (write only dead ws) ================
// Probe 1: R4 GEMM loop incl. staging, x4 reps, no epilogue.
__global__ __launch_bounds__(512, 2) void probe_gemm_full(
    const __hip_bfloat16* __restrict__ hin,
    const __hip_bfloat16* __restrict__ Bp,
    const float* __restrict__ biasv, float* __restrict__ dump) {
  extern __shared__ char lds[];
  const int tid = threadIdx.x;
  const int lane = tid & 63;
  const int w = tid >> 6;
  const int l15 = lane & 15, lhi = lane >> 4;
  const int wr = w >> 2, wc = w & 3;
  const int bi = blockIdx.x;
  const int xcd = bi & 7, slot = bi >> 3;
  const int bx = (xcd & 3) * 4 + (slot & 3);
  const int by = (xcd >> 2) * 8 + (slot >> 2);
  const int ucol = by * 64 + wc * 16 + l15;

  f32x4 acc[8][4];
#pragma unroll
  for (int g = 0; g < 4; ++g) {
    float bg = biasv[g * 1024 + ucol];
    asm volatile("" :: "v"(bg));
#pragma unroll
    for (int m = 0; m < 8; ++m) acc[m][g] = (f32x4){bg, bg, bg, bg};
  }
  const char* Asrc = (const char*)(hin + (size_t)bx * 256 * 1024);
  const char* Bsrc = (const char*)(Bp + (size_t)by * 256 * 1024);
  const int swz = (l15 & 7) << 4;

  auto STAGE = [&](const char* src, int rowoff, int kt, char* dstbase) {
#pragma unroll
    for (int i = 0; i < 2; ++i) {
      int chunk = i * 512 + tid;
      int row = chunk >> 3, s = chunk & 7;
      gload16(src + (size_t)(rowoff + row) * 2048 + kt * 128 +
                  ((s * 16) ^ ((row & 7) << 4)),
              dstbase + i * 8192 + w * 1024 + lane * 16);
    }
  };
  auto RD_A = [&](const char* Ab, int half, s16x8 (&d)[4][2]) {
#pragma unroll
    for (int m = 0; m < 4; ++m) {
      int row = half * 128 + wr * 64 + m * 16 + l15;
#pragma unroll
      for (int kk = 0; kk < 2; ++kk)
        d[m][kk] = *(const s16x8*)(Ab + row * 128 + ((kk * 64 + lhi * 16) ^ swz));
    }
  };
  auto RD_B = [&](const char* Bb, int half, s16x8 (&d)[2][2]) {
#pragma unroll
    for (int g = 0; g < 2; ++g) {
      int row = half * 128 + wc * 32 + g * 16 + l15;
#pragma unroll
      for (int kk = 0; kk < 2; ++kk)
        d[g][kk] = *(const s16x8*)(Bb + row * 128 + ((kk * 64 + lhi * 16) ^ swz));
    }
  };

  for (int rep = 0; rep < 4; ++rep) {
    STAGE(Asrc, 0,   0, lds);
    STAGE(Bsrc, 0,   0, lds + 32768);
    STAGE(Bsrc, 128, 0, lds + 32768 + 16384);
    STAGE(Asrc, 128, 0, lds + 16384);
    for (int kt = 0; kt < 16; ++kt) {
      const char* Ab = lds + (kt & 1) * 65536;
      const char* Bb = Ab + 32768;
      char* Sd = lds + ((kt + 1) & 1) * 65536;
      const bool pf = (kt < 15);
      s16x8 al[4][2], bl[2][2], bh[2][2], ah[4][2];
      asm volatile("s_waitcnt vmcnt(4)" ::: "memory");
      block_barrier();
      RD_A(Ab, 0, al); RD_B(Bb, 0, bl);
      if (pf) STAGE(Asrc, 0, kt + 1, Sd);
      asm volatile("s_waitcnt lgkmcnt(0)" ::: "memory");
      __builtin_amdgcn_sched_barrier(0);
      MMA(al, bl, 0, 0);
      if (pf) asm volatile("s_waitcnt vmcnt(4)" ::: "memory");
      else    asm volatile("s_waitcnt vmcnt(2)" ::: "memory");
      block_barrier();
      RD_B(Bb, 1, bh);
      if (pf) STAGE(Bsrc, 0, kt + 1, Sd + 32768);
      asm volatile("s_waitcnt lgkmcnt(0)" ::: "memory");
      __builtin_amdgcn_sched_barrier(0);
      MMA(al, bh, 0, 2);
      if (pf) asm volatile("s_waitcnt vmcnt(4)" ::: "memory");
      else    asm volatile("s_waitcnt vmcnt(0)" ::: "memory");
      block_barrier();
      RD_A(Ab, 1, ah);
      if (pf) STAGE(Bsrc, 128, kt + 1, Sd + 32768 + 16384);
      asm volatile("s_waitcnt lgkmcnt(0)" ::: "memory");
      __builtin_amdgcn_sched_barrier(0);
      MMA(ah, bh, 4, 2);
      if (pf) STAGE(Asrc, 128, kt + 1, Sd + 16384);
      MMA(ah, bl, 4, 0);
    }
  }
  float s = 0;
#pragma unroll
  for (int m = 0; m < 8; ++m)
#pragma unroll
    for (int g = 0; g < 4; ++g)
#pragma unroll
      for (int j = 0; j < 4; ++j) s += acc[m][g][j];
  dump[blockIdx.x * 512 + tid] = s;
}

// Probe 2: same loop, NO staging / NO vmcnt (reads stale LDS), x4 reps.
__global__ __launch_bounds__(512, 2) void probe_gemm_nostage(
    const __hip_bfloat16* __restrict__ hin,
    const __hip_bfloat16* __restrict__ Bp,
    const float* __restrict__ biasv, float* __restrict__ dump) {
  extern __shared__ char lds[];
  const int tid = threadIdx.x;
  const int lane = tid & 63;
  const int w = tid >> 6;
  const int l15 = lane & 15, lhi = lane >> 4;
  const int wr = w >> 2, wc = w & 3;
  const int ucol = wc * 16 + l15;

  f32x4 acc[8][4];
#pragma unroll
  for (int g = 0; g < 4; ++g) {
    float bg = biasv[g * 1024 + ucol];
#pragma unroll
    for (int m = 0; m < 8; ++m) acc[m][g] = (f32x4){bg, bg, bg, bg};
  }
  const int swz = (l15 & 7) << 4;
  auto RD_A = [&](const char* Ab, int half, s16x8 (&d)[4][2]) {
#pragma unroll
    for (int m = 0; m < 4; ++m) {
      int row = half * 128 + wr * 64 + m * 16 + l15;
#pragma unroll
      for (int kk = 0; kk < 2; ++kk)
        d[m][kk] = *(const s16x8*)(Ab + row * 128 + ((kk * 64 + lhi * 16) ^ swz));
    }
  };
  auto RD_B = [&](const char* Bb, int half, s16x8 (&d)[2][2]) {
#pragma unroll
    for (int g = 0; g < 2; ++g) {
      int row = half * 128 + wc * 32 + g * 16 + l15;
#pragma unroll
      for (int kk = 0; kk < 2; ++kk)
        d[g][kk] = *(const s16x8*)(Bb + row * 128 + ((kk * 64 + lhi * 16) ^ swz));
    }
  };
  block_barrier();
  for (int rep = 0; rep < 4; ++rep) {
    for (int kt = 0; kt < 16; ++kt) {
      const char* Ab = lds + (kt & 1) * 65536;
      const char* Bb = Ab + 32768;
      s16x8 al[4][2], bl[2][2], bh[2][2], ah[4][2];
      block_barrier();
      RD_A(Ab, 0, al); RD_B(Bb, 0, bl);
      asm volatile("s_waitcnt lgkmcnt(0)" ::: "memory");
      __builtin_amdgcn_sched_barrier(0);
      MMA(al, bl, 0, 0);
      block_barrier();
      RD_B(Bb, 1, bh);
      asm volatile("s_waitcnt lgkmcnt(0)" ::: "memory");
      __builtin_amdgcn_sched_barrier(0);
      MMA(al, bh, 0, 2);
      block_barrier();
      RD_A(Ab, 1, ah);
      asm volatile("s_waitcnt lgkmcnt(0)" ::: "memory");
      __builtin_amdgcn_sched_barrier(0);
      MMA(ah, bh, 4, 2);
      MMA(ah, bl, 4, 0);
    }
  }
  float s = 0;
#pragma unroll
  for (int m = 0; m < 8; ++m)
#pragma unroll
    for (int g = 0; g < 4; ++g)
#pragma unroll
      for (int j = 0; j < 4; ++j) s += acc[m][g][j];
  dump[blockIdx.x * 512 + tid] = s;
}

// Probe 3: epilogue only, x16 reps. Reads real cbuf; writes dead shadows.
__global__ __launch_bounds__(512, 2) void probe_epi(
    const float* __restrict__ c, __hip_bfloat16* __restrict__ hsh,
    float* __restrict__ adump, const float* __restrict__ dw) {
  const int tid = threadIdx.x;
  const int lane = tid & 63;
  const int w = tid >> 6;
  const int l15 = lane & 15, lhi = lane >> 4;
  const int wr = w >> 2, wc = w & 3;
  const int bi = blockIdx.x;
  const int xcd = bi & 7, slot = bi >> 3;
  const int bx = (xcd & 3) * 4 + (slot & 3);
  const int by = (xcd >> 2) * 8 + (slot >> 2);
  const int ucol = by * 64 + wc * 16 + l15;
  const float dwv = dw[ucol];
  for (int rep = 0; rep < 16; ++rep) {
#pragma unroll
    for (int m = 0; m < 8; ++m) {
#pragma unroll
      for (int j = 0; j < 4; ++j) {
        int b = bx * 256 + (m >> 2) * 128 + wr * 64 + (m & 3) * 16 + lhi * 4 + j;
        size_t ci = (size_t)b * 1024 + ucol;
        float cv = c[ci];
        float zi = cv * 1.01f, zf = cv * 0.99f, zg = cv * 1.02f, zo = cv * 0.98f;
        float ig = fsigmoid(zi), fg = fsigmoid(zf);
        float gg = ftanh(zg), og = fsigmoid(zo);
        float cn = fg * cv + ig * gg;
        float hn = og * ftanh(cn);
        hsh[ci] = __float2bfloat16(hn);
        float p = hn * dwv;
        p += __shfl_xor(p, 1);
        p += __shfl_xor(p, 2);
        p += __shfl_xor(p, 4);
        p += __shfl_xor(p, 8);
        if (l15 == 0) atomicAdd(&adump[(size_t)b * 32 + (rep & 31)], p);
      }
    }
  }
}

// Probe 4: 128x128-tile 2-phase counted-vmcnt GEMM, 2 blocks/CU, x4 reps.
__global__ __launch_bounds__(256, 2) void probe_g97(
    const __hip_bfloat16* __restrict__ hin,
    const __hip_bfloat16* __restrict__ Bp, float* __restrict__ dump) {
  extern __shared__ char lds[];   // 65536: A dbuf 2x16K @0, B dbuf 2x16K @32768
  const int tid = threadIdx.x;
  const int lane = tid & 63;
  const int w = tid >> 6;          // 0..3
  const int l15 = lane & 15, lhi = lane >> 4;
  const int wr = w >> 1, wc = w & 1;
  const char* Asrc = (const char*)(hin + (size_t)blockIdx.x * 128 * 1024);
  const char* Bsrc = (const char*)(Bp + (size_t)blockIdx.y * 128 * 1024);
  const int swz = (l15 & 7) << 4;
  f32x4 a9[4][4];
#pragma unroll
  for (int m = 0; m < 4; ++m)
#pragma unroll
    for (int g = 0; g < 4; ++g) a9[m][g] = (f32x4){0, 0, 0, 0};

  auto STG = [&](const char* src, int kt, char* dst) {  // 128 rows x 64k
#pragma unroll
    for (int i = 0; i < 4; ++i) {
      int chunk = i * 256 + tid;
      int row = chunk >> 3, s = chunk & 7;
      gload16(src + (size_t)row * 2048 + kt * 128 + ((s * 16) ^ ((row & 7) << 4)),
              dst + (i * 256 + w * 64) * 16 + lane * 16 - lane * 16 + lane * 16);
    }
  };
  // NOTE: dest must be wave-uniform + lane*16; chunk*16 == (i*256+w*64)*16 + lane*16.

  for (int rep = 0; rep < 4; ++rep) {
    STG(Asrc, 0, lds);
    STG(Bsrc, 0, lds + 32768);
    for (int kt = 0; kt < 16; ++kt) {
      char* Ab = lds + (kt & 1) * 16384;
      char* Bb = lds + 32768 + (kt & 1) * 16384;
      if (kt < 15) {
        STG(Asrc, kt + 1, lds + ((kt + 1) & 1) * 16384);
        STG(Bsrc, kt + 1, lds + 32768 + ((kt + 1) & 1) * 16384);
        asm volatile("s_waitcnt vmcnt(8)" ::: "memory");
      } else {
        asm volatile("s_waitcnt vmcnt(0)" ::: "memory");
      }
      block_barrier();
      s16x8 af[4][2], bf[4][2];
#pragma unroll
      for (int m = 0; m < 4; ++m) {
        int row = wr * 64 + m * 16 + l15;
#pragma unroll
        for (int kk = 0; kk < 2; ++kk)
          af[m][kk] = *(const s16x8*)(Ab + row * 128 + ((kk * 64 + lhi * 16) ^ swz));
      }
#pragma unroll
      for (int g = 0; g < 4; ++g) {
        int row = wc * 64 + g * 16 + l15;
#pragma unroll
        for (int kk = 0; kk < 2; ++kk)
          bf[g][kk] = *(const s16x8*)(Bb + row * 128 + ((kk * 64 + lhi * 16) ^ swz));
      }
      asm volatile("s_waitcnt lgkmcnt(0)" ::: "memory");
      __builtin_amdgcn_sched_barrier(0);
      __builtin_amdgcn_s_setprio(1);
#pragma unroll
      for (int m = 0; m < 4; ++m)
#pragma unroll
        for (int g = 0; g < 4; ++g)
#pragma unroll
          for (int kk = 0; kk < 2; ++kk)
            a9[m][g] = __builtin_amdgcn_mfma_f32_16x16x32_bf16(
                af[m][kk], bf[g][kk], a9[m][g], 0, 0, 0);
      __builtin_amdgcn_s_setprio(0);
      block_barrier();
    }
  }
  float s = 0;
#pragma unroll
  for (int m = 0; m < 4; ++m)
#pragma unroll
    for (int g = 0; g < 4; ++g)
#pragma unroll
      for (int j = 0; j < 4; ++j) s += a9[m][g][j];
  dump[((size_t)blockIdx.y * 32 + blockIdx.x) * 256 + tid] = s;
}

extern "C" void kernel_launch(void* const* d_in, const int* in_sizes, int n_in,
                              void* d_out, int out_size, void* d_ws, size_t ws_size,
                              hipStream_t stream) {
  const float* feat = (const float*)d_in[0];  // [4096][512]
  const float* ker  = (const float*)d_in[1];  // [1][4096]
  const float* R    = (const float*)d_in[2];  // [1024][4096]
  const float* bias = (const float*)d_in[3];  // [4096]
  const float* dw   = (const float*)d_in[4];  // [1024][1]
  const float* db   = (const float*)d_in[5];  // [1]
  float* out = (float*)d_out;

  char* ws = (char*)d_ws;
  const size_t MB = 1024 * 1024;
  __hip_bfloat16* Rt0 = (__hip_bfloat16*)(ws);            // 8 MB (permuted)
  __hip_bfloat16* Rt1 = (__hip_bfloat16*)(ws + 8 * MB);   // 8 MB (permuted+fold)
  float* bias1 = (float*)(ws + 16 * MB);                  // 16 KB
  __hip_bfloat16* hA = (__hip_bfloat16*)(ws + 16 * MB + 65536);  // 8 MB
  __hip_bfloat16* hB = (__hip_bfloat16*)(ws + 24 * MB + 65536);  // 8 MB
  float* cbuf = (float*)(ws + 32 * MB + 65536);           // 16 MB

  hipFuncSetAttribute((const void*)lstm_step,
                      hipFuncAttributeMaxDynamicSharedMemorySize, 131072);
  hipFuncSetAttribute((const void*)probe_gemm_full,
                      hipFuncAttributeMaxDynamicSharedMemorySize, 131072);
  hipFuncSetAttribute((const void*)probe_gemm_nostage,
                      hipFuncAttributeMaxDynamicSharedMemorySize, 131072);
  hipFuncSetAttribute((const void*)probe_g97,
                      hipFuncAttributeMaxDynamicSharedMemorySize, 65536);

  prep_weights<<<dim3(128, 32), dim3(32, 8), 0, stream>>>(R, ker, dw, Rt0, Rt1);
  prep_state<<<4096, 256, 0, stream>>>(feat, bias, ker, db, bias1, hA, cbuf, out);

  for (int t = 0; t < NSTEP; ++t) {
    const __hip_bfloat16* hin = (t & 1) ? hB : hA;
    __hip_bfloat16* hout = (t & 1) ? hA : hB;
    lstm_step<<<256, 512, 131072, stream>>>(
        hin, (t == 0) ? Rt0 : Rt1, (t == 0) ? bias : bias1, cbuf, hout, dw, out, t);
  }

  // ---- ablation probes: touch only dead ws regions, never d_out.
  probe_gemm_full<<<256, 512, 131072, stream>>>(hA, Rt1, bias1, (float*)cbuf);
  probe_gemm_nostage<<<256, 512, 131072, stream>>>(hA, Rt1, bias1,
                                                   (float*)cbuf + 140000);
  probe_epi<<<256, 512, 0, stream>>>(cbuf, Rt0, (float*)hB, dw);
  probe_g97<<<dim3(32, 32), 256, 65536, stream>>>(hA, Rt1,
                                                  (float*)cbuf + 300000);
}